// Round 4
// baseline (646.564 us; speedup 1.0000x reference)
//
#include <hip/hip_runtime.h>
#include <stdint.h>

// EdgeMessage: message[e,m] = sum_v (edges[e,:]@W[m*64+v,:] + b[m*64+v]) * vertices[e,v]
// R10: triple the schedulable waves/SIMD (the one counter that never moved).
//  - R8/R9 pinned at 1.53 waves/SIMD (grid-invariant: E/64 waves). All stall
//    hypotheses tied to per-wave latency exposure with no co-resident cover.
//  - block = 128 edges, 4 waves; wave (h,nh) owns 64 edges x 32 cols (quadrant).
//    grid = 782 blocks -> 3128 waves; LDS 48 KB -> 3 blocks/CU -> 3.05 waves/SIMD,
//    3 independent barrier groups per CU (stalled block covered by other two).
//  - W staged in 8 KB HALF-steps (s in {2p,2p+1}), ring of 4 (32 KB), via
//    global_load_lds; 2 gloads/wave/half-step; counted vmcnt(4), never drained.
//    Prefetch window ~2.5 half-steps + TLP cover.
//  - Vt 16 KB ([64][128] f16, broadcast-read); per half-step: 4 ds_read_b128 (B),
//    16 MFMA, 32 pk_mul. Bias folded as 2 K-steps on the wave's column pair.

typedef _Float16 f16;
typedef __attribute__((ext_vector_type(2))) _Float16 f16x2;
typedef __attribute__((ext_vector_type(8))) _Float16 f16x8;
typedef __attribute__((ext_vector_type(4))) float f32x4;

#define MSG_D 64
#define VTX_D 64
#define EDG_D 128

__device__ __forceinline__ f16x8 cvt8(float4 a, float4 d) {
  return (f16x8){(f16)a.x, (f16)a.y, (f16)a.z, (f16)a.w,
                 (f16)d.x, (f16)d.y, (f16)d.z, (f16)d.w};
}

// ---- prep: W -> fragment stream; b -> bias frags (layout same as R5..R9) ----
// Wh granule tid = (v*16 + c)*64 + lane (c = s*4+n): f16[8] =
//   W[(n*16+ln)*64 + v][s*32 + q*8 + j], lane = q*16+ln.
__global__ void prep_w(const float* __restrict__ W, const float* __restrict__ b,
                       f16* __restrict__ Wh, f16* __restrict__ Bh) {
  int tid = blockIdx.x * 256 + threadIdx.x;
  if (tid < 65536) {
    int L = tid & 63, n = (tid >> 6) & 3, s = (tid >> 8) & 3, v = tid >> 10;
    int q = L >> 4, ln = L & 15;
    const float* src = W + (size_t)((n * 16 + ln) * 64 + v) * 128 + s * 32 + q * 8;
    float4 a = *(const float4*)src, d = *(const float4*)(src + 4);
    *(f16x8*)(Wh + (size_t)tid * 8) = cvt8(a, d);
  } else if (tid < 66048) {
    int t2 = tid - 65536;
    int L = t2 & 63, n = (t2 >> 6) & 3, s2 = t2 >> 8;
    int q = L >> 4, ln = L & 15;
    const float* src = b + (n * 16 + ln) * 64 + s2 * 32 + q * 8;
    float4 a = *(const float4*)src, d = *(const float4*)(src + 4);
    *(f16x8*)(Bh + (size_t)t2 * 8) = cvt8(a, d);
  }
}

// async global->LDS, 16B per lane, wave-uniform LDS base (+lane*16 implicit)
typedef __attribute__((address_space(1))) const void GV;
typedef __attribute__((address_space(3))) void LV;
__device__ __forceinline__ void gload_lds16(const void* g, void* l) {
  __builtin_amdgcn_global_load_lds((GV*)g, (LV*)l, 16, 0, 0);
}

// ---- main kernel: 256 threads = 4 waves; 128-edge block, quadrant waves ----
__global__ __launch_bounds__(256, 3) void edge_msg_lds(
    const float* __restrict__ Vtx, const float* __restrict__ Xe,
    const f16* __restrict__ Wh, const f16* __restrict__ Bh,
    float* __restrict__ out, int E)
{
  __shared__ f16 Wring[4 * 4096];   // 32 KB: ring of 4 half-step buffers (8 KB each)
  __shared__ f16 Vt[64 * 128];      // 16 KB: V transposed f16 [v][local_e]

  const int tid = threadIdx.x;
  const int wid = tid >> 6, lane = tid & 63;
  const int q = lane >> 4, ln = lane & 15;
  const int h = wid >> 1, nh = wid & 1;   // edge-half, col-half of this wave
  const int eblk = blockIdx.x * 128;
  const int eoff = eblk + h * 64;

  // ---- X fragments f16 (A[m=ln][k=q*8+j] per t,s), rows clamped ----
  int er[4];
  f16x8 xh[4][4];
  #pragma unroll
  for (int t = 0; t < 4; ++t) {
    int e = eoff + 16 * t + ln;
    er[t] = e < E ? e : E - 1;
    const float* xr = Xe + (size_t)er[t] * EDG_D;
    #pragma unroll
    for (int s = 0; s < 4; ++s) {
      float4 a = *(const float4*)(xr + s * 32 + q * 8);
      float4 d = *(const float4*)(xr + s * 32 + q * 8 + 4);
      xh[t][s] = cvt8(a, d);
    }
  }

  // ---- stage V transposed: thread (e'=tid&127, vhalf=tid>>7) ----
  {
    int el = tid & 127;
    int e2 = eblk + el;
    int ec = e2 < E ? e2 : E - 1;
    int vbase = (tid >> 7) * 32;
    const float* vr = Vtx + (size_t)ec * VTX_D + vbase;
    #pragma unroll
    for (int k8 = 0; k8 < 4; ++k8) {
      float4 a = *(const float4*)(vr + k8 * 8);
      float4 d = *(const float4*)(vr + k8 * 8 + 4);
      int v = vbase + k8 * 8;
      Vt[(v + 0) * 128 + el] = (f16)a.x;
      Vt[(v + 1) * 128 + el] = (f16)a.y;
      Vt[(v + 2) * 128 + el] = (f16)a.z;
      Vt[(v + 3) * 128 + el] = (f16)a.w;
      Vt[(v + 4) * 128 + el] = (f16)d.x;
      Vt[(v + 5) * 128 + el] = (f16)d.y;
      Vt[(v + 6) * 128 + el] = (f16)d.z;
      Vt[(v + 7) * 128 + el] = (f16)d.w;
    }
  }

  f32x4 acc[4][2];
  #pragma unroll
  for (int t = 0; t < 4; ++t)
    #pragma unroll
    for (int nn = 0; nn < 2; ++nn) acc[t][nn] = (f32x4){0.f, 0.f, 0.f, 0.f};

  // ---- prologue: stage half-steps 0,1,2 (wave stages granules c'=wid*2, +1) ----
  // Wh bytes: half-step k (v=k>>1, p=k&1) at v*16384 + p*8192; granule c' at +c'*1024.
  {
    const size_t wl = (size_t)(wid * 2) * 1024 + (size_t)lane * 16;
    #pragma unroll
    for (int k = 0; k < 3; ++k) {
      const char* g = (const char*)Wh + (size_t)(k >> 1) * 16384 + (size_t)(k & 1) * 8192 + wl;
      char* l = (char*)&Wring[(k & 3) * 4096] + (wid * 2) * 1024;
      gload_lds16(g, l);
      gload_lds16(g + 1024, l + 1024);
    }
  }

  // V writes visible to all waves before loop
  asm volatile("s_waitcnt lgkmcnt(0)" ::: "memory");
  __builtin_amdgcn_s_barrier();
  asm volatile("" ::: "memory");

  #pragma unroll 1
  for (int k = 0; k < 128; ++k) {
    const int v = k >> 1, p = k & 1;

    // own granules for half-step k complete (next 2 half-steps stay in flight)
    if (k == 127)      asm volatile("s_waitcnt vmcnt(0)" ::: "memory");
    else if (k == 126) asm volatile("s_waitcnt vmcnt(2)" ::: "memory");
    else               asm volatile("s_waitcnt vmcnt(4)" ::: "memory");
    __builtin_amdgcn_s_barrier();
    asm volatile("" ::: "memory");   // no LDS reads / stage issues above this point

    // stage half-step k+3 into buf (k+3)&3 (freed by barrier above)
    if (k < 125) {
      const int k3 = k + 3;
      const char* g = (const char*)Wh + (size_t)(k3 >> 1) * 16384 + (size_t)(k3 & 1) * 8192 +
                      (size_t)(wid * 2) * 1024 + (size_t)lane * 16;
      char* l = (char*)&Wring[(k3 & 3) * 4096] + (wid * 2) * 1024;
      gload_lds16(g, l);
      gload_lds16(g + 1024, l + 1024);
    }

    // per-edge V broadcast for this v (transposed LDS, broadcast within 16-lane groups)
    f16x2 hv[4];
    #pragma unroll
    for (int t = 0; t < 4; ++t) {
      f16 hh = Vt[v * 128 + h * 64 + 16 * t + ln];
      hv[t] = (f16x2){hh, hh};
    }

    __builtin_amdgcn_s_setprio(1);
    const f16* wb = &Wring[(k & 3) * 4096 + lane * 8];
    // wave's granules within half-buffer: c'' = sl*4 + (2*nh + nn)
    f16x8 bf[4];
    #pragma unroll
    for (int sl = 0; sl < 2; ++sl)
      #pragma unroll
      for (int nn = 0; nn < 2; ++nn)
        bf[sl * 2 + nn] = *(const f16x8*)(wb + (sl * 4 + 2 * nh + nn) * 512);

    #pragma unroll
    for (int sl = 0; sl < 2; ++sl) {
      const int s = 2 * p + sl;
      f16x8 af[4];
      #pragma unroll
      for (int t = 0; t < 4; ++t) {
        union { f16x8 v8; f16x2 h2[4]; } x, r;
        x.v8 = xh[t][s];
        r.h2[0] = hv[t] * x.h2[0];
        r.h2[1] = hv[t] * x.h2[1];
        r.h2[2] = hv[t] * x.h2[2];
        r.h2[3] = hv[t] * x.h2[3];
        af[t] = r.v8;
      }
      #pragma unroll
      for (int nn = 0; nn < 2; ++nn)
        #pragma unroll
        for (int t = 0; t < 4; ++t)
          acc[t][nn] = __builtin_amdgcn_mfma_f32_16x16x32_f16(af[t], bf[sl * 2 + nn], acc[t][nn], 0, 0, 0);
    }
    __builtin_amdgcn_s_setprio(0);
  }

  // ---- bias: 2 K-steps, A = V-frags (original layout), B = Bh frags (col pair) ----
  #pragma unroll
  for (int s2 = 0; s2 < 2; ++s2) {
    f16x8 av[4];
    #pragma unroll
    for (int t = 0; t < 4; ++t) {
      const float* vr2 = Vtx + (size_t)er[t] * VTX_D + s2 * 32 + q * 8;
      float4 a = *(const float4*)vr2, d = *(const float4*)(vr2 + 4);
      av[t] = cvt8(a, d);
    }
    #pragma unroll
    for (int nn = 0; nn < 2; ++nn) {
      const int n = 2 * nh + nn;
      f16x8 bfb = *(const f16x8*)(Bh + (size_t)((s2 * 4 + n) * 64 + lane) * 8);
      #pragma unroll
      for (int t = 0; t < 4; ++t)
        acc[t][nn] = __builtin_amdgcn_mfma_f32_16x16x32_f16(av[t], bfb, acc[t][nn], 0, 0, 0);
    }
  }

  // ---- store: C layout col=lane&15 (m), row=q*4+r (edge) [m89-verified] ----
  #pragma unroll
  for (int t = 0; t < 4; ++t)
    #pragma unroll
    for (int r = 0; r < 4; ++r) {
      int e = eoff + 16 * t + 4 * q + r;
      if (e < E) {
        float* orow = out + (size_t)e * MSG_D;
        #pragma unroll
        for (int nn = 0; nn < 2; ++nn) orow[(2 * nh + nn) * 16 + ln] = acc[t][nn][r];
      }
    }
}

// ---- fallback (workspace too small / unexpected shape): exact fp32 ----
__global__ void edge_msg_naive(const float* __restrict__ Vtx, const float* __restrict__ Xe,
                               const float* __restrict__ W, const float* __restrict__ b,
                               float* __restrict__ out, int E) {
  __shared__ float xs[EDG_D];
  __shared__ float vs[VTX_D];
  int e = blockIdx.x;
  int m = threadIdx.x;
  for (int i = m; i < EDG_D; i += 64) xs[i] = Xe[(size_t)e * EDG_D + i];
  for (int i = m; i < VTX_D; i += 64) vs[i] = Vtx[(size_t)e * VTX_D + i];
  __syncthreads();
  float s = 0.f;
  for (int v = 0; v < VTX_D; ++v) {
    const float* wr = W + (size_t)(m * 64 + v) * EDG_D;
    float p = b[m * 64 + v];
    for (int k = 0; k < EDG_D; ++k) p += xs[k] * wr[k];
    s += p * vs[v];
  }
  out[(size_t)e * MSG_D + m] = s;
}

extern "C" void kernel_launch(void* const* d_in, const int* in_sizes, int n_in,
                              void* d_out, int out_size, void* d_ws, size_t ws_size,
                              hipStream_t stream) {
  const float* Vtx = (const float*)d_in[0];   // [E, 64]
  const float* Xe  = (const float*)d_in[1];   // [E, 128]
  const float* W   = (const float*)d_in[2];   // [4096, 128]
  const float* b   = (const float*)d_in[3];   // [4096]
  float* out = (float*)d_out;

  const int E  = in_sizes[0] / VTX_D;
  const int nW = in_sizes[2];                 // 524288
  const int nb = in_sizes[3];                 // 4096

  const size_t needW = (size_t)(524288 + 4096) * sizeof(f16);   // ~1.01 MB

  if (nW != 524288 || nb != 4096 || ws_size < needW) {
    edge_msg_naive<<<E, 64, 0, stream>>>(Vtx, Xe, W, b, out, E);
    return;
  }

  f16* Wh = (f16*)d_ws;
  f16* Bh = Wh + 524288;

  prep_w<<<258, 256, 0, stream>>>(W, b, Wh, Bh);

  int blocks = (E + 127) / 128;
  edge_msg_lds<<<blocks, 256, 0, stream>>>(Vtx, Xe, Wh, Bh, out, E);
}

// Round 5
// 266.802 us; speedup vs baseline: 2.4234x; 2.4234x over previous
//
#include <hip/hip_runtime.h>
#include <stdint.h>

// EdgeMessage: message[e,m] = sum_v (edges[e,:]@W[m*64+v,:] + b[m*64+v]) * vertices[e,v]
// R11: balanced residency + depth-4 W pipeline. (R10 post-mortem: >2 blocks/CU breaks
// the chip-wide phase-lock on the W stream -> L2 thrash at 2 TB/s fabric; stay at 2/CU.)
//  - grid 521 x 192 thr (3 waves, 64e x 64m tiles): 2.03 blocks/CU BALANCED (vs R8's
//    391 blocks over 512 slots: 121 CUs half-idle). Load-balance alone ~ -24%.
//  - W ring: 5 x 16 KB = 80 KB LDS (all of it), staged via global_load_lds,
//    prefetch lead 4 steps (vs R8's 2): step i staged at iter i-4.
//  - V in REGISTERS (R6 chunk scheme): no Vt LDS; chunk c8+1 loaded at inner j==6,
//    inside asm-fence windows. Manual vmcnt constants are oldest-drain-safe:
//    W(i) is always the oldest outstanding group, so vmcnt(3*own_cnt) drains it
//    regardless of interleaved V loads (V only adds over-wait, never under-wait).
//  - per-wave granules g = wid+3k (w0:6, w1/w2:5) -> per-wave wait constants 18/15,
//    tail iters 61/62/63 use 12/10, 6/5, 0.
//  - phase-locked stream (no stagger), zero LDS bank conflicts, bias as 2 K-steps.

typedef _Float16 f16;
typedef __attribute__((ext_vector_type(2))) _Float16 f16x2;
typedef __attribute__((ext_vector_type(8))) _Float16 f16x8;
typedef __attribute__((ext_vector_type(4))) float f32x4;

#define MSG_D 64
#define VTX_D 64
#define EDG_D 128

__device__ __forceinline__ f16x8 cvt8(float4 a, float4 d) {
  return (f16x8){(f16)a.x, (f16)a.y, (f16)a.z, (f16)a.w,
                 (f16)d.x, (f16)d.y, (f16)d.z, (f16)d.w};
}

// ---- prep: W -> fragment stream; b -> bias frags (layout same as R5..R10) ----
// Wh granule tid = (v*16 + c)*64 + lane (c = s*4+n): f16[8] =
//   W[(n*16+ln)*64 + v][s*32 + q*8 + j], lane = q*16+ln.
__global__ void prep_w(const float* __restrict__ W, const float* __restrict__ b,
                       f16* __restrict__ Wh, f16* __restrict__ Bh) {
  int tid = blockIdx.x * 256 + threadIdx.x;
  if (tid < 65536) {
    int L = tid & 63, n = (tid >> 6) & 3, s = (tid >> 8) & 3, v = tid >> 10;
    int q = L >> 4, ln = L & 15;
    const float* src = W + (size_t)((n * 16 + ln) * 64 + v) * 128 + s * 32 + q * 8;
    float4 a = *(const float4*)src, d = *(const float4*)(src + 4);
    *(f16x8*)(Wh + (size_t)tid * 8) = cvt8(a, d);
  } else if (tid < 66048) {
    int t2 = tid - 65536;
    int L = t2 & 63, n = (t2 >> 6) & 3, s2 = t2 >> 8;
    int q = L >> 4, ln = L & 15;
    const float* src = b + (n * 16 + ln) * 64 + s2 * 32 + q * 8;
    float4 a = *(const float4*)src, d = *(const float4*)(src + 4);
    *(f16x8*)(Bh + (size_t)t2 * 8) = cvt8(a, d);
  }
}

// async global->LDS, 16B per lane, wave-uniform LDS base (+lane*16 implicit)
typedef __attribute__((address_space(1))) const void GV;
typedef __attribute__((address_space(3))) void LV;
__device__ __forceinline__ void gload_lds16(const void* g, void* l) {
  __builtin_amdgcn_global_load_lds((GV*)g, (LV*)l, 16, 0, 0);
}

// ---- main kernel: 192 threads = 3 waves; ring-5 LDS W stream, V in regs ----
__global__ __launch_bounds__(192, 2) void edge_msg_lds(
    const float* __restrict__ Vtx, const float* __restrict__ Xe,
    const f16* __restrict__ Wh, const f16* __restrict__ Bh,
    float* __restrict__ out, int E)
{
  __shared__ f16 Wring[5 * 8192];   // 80 KB: ring of 5 step-buffers (16 KB each)

  const int tid = threadIdx.x;
  const int wid = tid >> 6, lane = tid & 63;
  const int q = lane >> 4, ln = lane & 15;
  const int eoff = blockIdx.x * 192 + wid * 64;

  // ---- X fragments f16 (A[m=ln][k=q*8+j] per t,s), rows clamped ----
  int er[4];
  f16x8 xh[4][4];
  #pragma unroll
  for (int t = 0; t < 4; ++t) {
    int e = eoff + 16 * t + ln;
    er[t] = e < E ? e : E - 1;
    const float* xr = Xe + (size_t)er[t] * EDG_D;
    #pragma unroll
    for (int s = 0; s < 4; ++s) {
      float4 a = *(const float4*)(xr + s * 32 + q * 8);
      float4 d = *(const float4*)(xr + s * 32 + q * 8 + 4);
      xh[t][s] = cvt8(a, d);
    }
  }

  // ---- V chunk 0 (v = 0..7) per t, f32 -> f16x8 (registers, no LDS) ----
  f16x8 vrow[4];
  #pragma unroll
  for (int t = 0; t < 4; ++t) {
    const float* vsrc = Vtx + (size_t)er[t] * VTX_D;
    float4 a = *(const float4*)(vsrc), d = *(const float4*)(vsrc + 4);
    vrow[t] = cvt8(a, d);
  }

  f32x4 acc[4][4];
  #pragma unroll
  for (int t = 0; t < 4; ++t)
    #pragma unroll
    for (int n = 0; n < 4; ++n) acc[t][n] = (f32x4){0.f, 0.f, 0.f, 0.f};

  // ---- prologue: stage steps 0..3 into slots 0..3 ----
  // Wh bytes: granule (v,g) at v*16384 + g*1024 + lane*16; wave wid owns g = wid+3k.
  {
    const char* gb = (const char*)Wh + (size_t)lane * 16;
    #pragma unroll
    for (int v = 0; v < 4; ++v) {
      char* lb = (char*)Wring + (size_t)v * 16384;
      #pragma unroll
      for (int k = 0; k < 6; ++k) {
        int g = wid + 3 * k;
        if (g < 16) gload_lds16(gb + (size_t)v * 16384 + g * 1024, lb + g * 1024);
      }
    }
  }

  int cur = 0;   // slot of step i
  int st  = 4;   // slot of step i+4

  #pragma unroll 1
  for (int c8 = 0; c8 < 8; ++c8) {
    float4 vna[4], vnd[4];   // next V chunk (loaded at j==6)

    #pragma unroll
    for (int j = 0; j < 8; ++j) {
      const int i = c8 * 8 + j;

      // wait for own step-i granules (older groups drain first; V loads among the
      // newer set only deepen the drain -> unconditionally safe constants)
      if (i < 61) {
        if (wid == 0) asm volatile("s_waitcnt vmcnt(18)" ::: "memory");
        else          asm volatile("s_waitcnt vmcnt(15)" ::: "memory");
      } else if (i == 61) {
        if (wid == 0) asm volatile("s_waitcnt vmcnt(12)" ::: "memory");
        else          asm volatile("s_waitcnt vmcnt(10)" ::: "memory");
      } else if (i == 62) {
        if (wid == 0) asm volatile("s_waitcnt vmcnt(6)" ::: "memory");
        else          asm volatile("s_waitcnt vmcnt(5)" ::: "memory");
      } else {
        asm volatile("s_waitcnt vmcnt(0)" ::: "memory");
      }
      __builtin_amdgcn_s_barrier();
      asm volatile("" ::: "memory");   // fence: nothing moves across the barrier

      // stage step i+4 into slot st (freed: consumed as step i-1, synced above)
      if (i < 60) {
        const char* gb = (const char*)Wh + (size_t)(i + 4) * 16384 + (size_t)lane * 16;
        char* lb = (char*)Wring + (size_t)st * 16384;
        #pragma unroll
        for (int k = 0; k < 6; ++k) {
          int g = wid + 3 * k;
          if (g < 16) gload_lds16(gb + g * 1024, lb + g * 1024);
        }
      }

      // next V chunk loads, pinned into this fence window (counts stay deterministic)
      if (j == 6 && c8 < 7) {
        #pragma unroll
        for (int t = 0; t < 4; ++t) {
          const float* vsrc = Vtx + (size_t)er[t] * VTX_D + (c8 + 1) * 8;
          vna[t] = *(const float4*)(vsrc);
          vnd[t] = *(const float4*)(vsrc + 4);
        }
      }

      // per-edge V broadcast for this v (register extract, j static)
      f16x2 hv[4];
      #pragma unroll
      for (int t = 0; t < 4; ++t) { f16 h = vrow[t][j]; hv[t] = (f16x2){h, h}; }

      const f16* wb = Wring + (size_t)cur * 8192 + lane * 8;
      #pragma unroll
      for (int s = 0; s < 4; ++s) {
        f16x8 bf[4];
        #pragma unroll
        for (int n = 0; n < 4; ++n) bf[n] = *(const f16x8*)(wb + (s * 4 + n) * 512);

        f16x8 af[4];
        #pragma unroll
        for (int t = 0; t < 4; ++t) {
          union { f16x8 v8; f16x2 h2[4]; } x, r;
          x.v8 = xh[t][s];
          r.h2[0] = hv[t] * x.h2[0];
          r.h2[1] = hv[t] * x.h2[1];
          r.h2[2] = hv[t] * x.h2[2];
          r.h2[3] = hv[t] * x.h2[3];
          af[t] = r.v8;
        }
        #pragma unroll
        for (int n = 0; n < 4; ++n)
          #pragma unroll
          for (int t = 0; t < 4; ++t)
            acc[t][n] = __builtin_amdgcn_mfma_f32_16x16x32_f16(af[t], bf[n], acc[t][n], 0, 0, 0);
      }

      cur = (cur == 4) ? 0 : cur + 1;
      st  = (st  == 4) ? 0 : st  + 1;
    }

    if (c8 < 7) {
      #pragma unroll
      for (int t = 0; t < 4; ++t) vrow[t] = cvt8(vna[t], vnd[t]);
    }
  }

  // ---- bias: 2 K-steps, A = V-frags (original layout), B = Bh frags ----
  #pragma unroll
  for (int s2 = 0; s2 < 2; ++s2) {
    f16x8 av[4];
    #pragma unroll
    for (int t = 0; t < 4; ++t) {
      const float* vr2 = Vtx + (size_t)er[t] * VTX_D + s2 * 32 + q * 8;
      float4 a = *(const float4*)vr2, d = *(const float4*)(vr2 + 4);
      av[t] = cvt8(a, d);
    }
    #pragma unroll
    for (int n = 0; n < 4; ++n) {
      f16x8 bfb = *(const f16x8*)(Bh + (size_t)((s2 * 4 + n) * 64 + lane) * 8);
      #pragma unroll
      for (int t = 0; t < 4; ++t)
        acc[t][n] = __builtin_amdgcn_mfma_f32_16x16x32_f16(av[t], bfb, acc[t][n], 0, 0, 0);
    }
  }

  // ---- store: C layout col=lane&15 (m), row=q*4+r (edge) [m89-verified] ----
  #pragma unroll
  for (int t = 0; t < 4; ++t)
    #pragma unroll
    for (int r = 0; r < 4; ++r) {
      int e = eoff + 16 * t + 4 * q + r;
      if (e < E) {
        float* orow = out + (size_t)e * MSG_D;
        #pragma unroll
        for (int n = 0; n < 4; ++n) orow[n * 16 + ln] = acc[t][n][r];
      }
    }
}

// ---- fallback (workspace too small / unexpected shape): exact fp32 ----
__global__ void edge_msg_naive(const float* __restrict__ Vtx, const float* __restrict__ Xe,
                               const float* __restrict__ W, const float* __restrict__ b,
                               float* __restrict__ out, int E) {
  __shared__ float xs[EDG_D];
  __shared__ float vs[VTX_D];
  int e = blockIdx.x;
  int m = threadIdx.x;
  for (int i = m; i < EDG_D; i += 64) xs[i] = Xe[(size_t)e * EDG_D + i];
  for (int i = m; i < VTX_D; i += 64) vs[i] = Vtx[(size_t)e * VTX_D + i];
  __syncthreads();
  float s = 0.f;
  for (int v = 0; v < VTX_D; ++v) {
    const float* wr = W + (size_t)(m * 64 + v) * EDG_D;
    float p = b[m * 64 + v];
    for (int k = 0; k < EDG_D; ++k) p += xs[k] * wr[k];
    s += p * vs[v];
  }
  out[(size_t)e * MSG_D + m] = s;
}

extern "C" void kernel_launch(void* const* d_in, const int* in_sizes, int n_in,
                              void* d_out, int out_size, void* d_ws, size_t ws_size,
                              hipStream_t stream) {
  const float* Vtx = (const float*)d_in[0];   // [E, 64]
  const float* Xe  = (const float*)d_in[1];   // [E, 128]
  const float* W   = (const float*)d_in[2];   // [4096, 128]
  const float* b   = (const float*)d_in[3];   // [4096]
  float* out = (float*)d_out;

  const int E  = in_sizes[0] / VTX_D;
  const int nW = in_sizes[2];                 // 524288
  const int nb = in_sizes[3];                 // 4096

  const size_t needW = (size_t)(524288 + 4096) * sizeof(f16);   // ~1.01 MB

  if (nW != 524288 || nb != 4096 || ws_size < needW) {
    edge_msg_naive<<<E, 64, 0, stream>>>(Vtx, Xe, W, b, out, E);
    return;
  }

  f16* Wh = (f16*)d_ws;
  f16* Bh = Wh + 524288;

  prep_w<<<258, 256, 0, stream>>>(W, b, Wh, Bh);

  int blocks = (E + 191) / 192;
  edge_msg_lds<<<blocks, 192, 0, stream>>>(Vtx, Xe, Wh, Bh, out, E);
}

// Round 6
// 202.614 us; speedup vs baseline: 3.1911x; 1.3168x over previous
//
#include <hip/hip_runtime.h>
#include <stdint.h>

// EdgeMessage: message[e,m] = sum_v (edges[e,:]@W[m*64+v,:] + b[m*64+v]) * vertices[e,v]
// R12: R8 shell, half the syncs, double the MFMA cluster.
//  - R8 (125us, best) = 256-edge 4-wave blocks, per-v-step {vmcnt,barrier}: 64 syncs.
//    MFMA floor is ~50us (105 GFLOP @ 2075 TF) -> ~60% of each step is sync/dep.
//    R9 ruled out L2 hotspot; R11 ruled out prefetch depth. Remaining: sync cadence.
//  - W ring: 4 x 16 KB slots (64 KB), consumed in 2-step WINDOWS. One
//    {vmcnt(0)-stale, barrier, stage-2-steps} per window: 33 syncs, 128 MFMA/wave
//    contiguous between barriers. Stage goes into the slots freed by the window
//    just consumed (after its barrier); the awaited batch is always one full
//    window old (~1200+ cyc) -> wait is cheap; batch never awaited younger.
//  - V in registers (R6 chunk scheme): chunk c8+1 loaded in window w4==2 of c8,
//    drained by that window's trailing sync, consumed next c8. No LDS hv chain
//    after the barrier (was ~150 cyc serial per step in R8).
//  - LDS 64 KB -> 2 blocks/CU (phase-locked pair preserved; R10 proved >2 thrashes).
//  - bias folded as 2 extra K-steps; store layout m89-verified.

typedef _Float16 f16;
typedef __attribute__((ext_vector_type(2))) _Float16 f16x2;
typedef __attribute__((ext_vector_type(8))) _Float16 f16x8;
typedef __attribute__((ext_vector_type(4))) float f32x4;

#define MSG_D 64
#define VTX_D 64
#define EDG_D 128

__device__ __forceinline__ f16x8 cvt8(float4 a, float4 d) {
  return (f16x8){(f16)a.x, (f16)a.y, (f16)a.z, (f16)a.w,
                 (f16)d.x, (f16)d.y, (f16)d.z, (f16)d.w};
}

// ---- prep: W -> fragment stream; b -> bias frags (layout same as R5..R11) ----
// Wh granule tid = (v*16 + c)*64 + lane (c = s*4+n): f16[8] =
//   W[(n*16+ln)*64 + v][s*32 + q*8 + j], lane = q*16+ln.
__global__ void prep_w(const float* __restrict__ W, const float* __restrict__ b,
                       f16* __restrict__ Wh, f16* __restrict__ Bh) {
  int tid = blockIdx.x * 256 + threadIdx.x;
  if (tid < 65536) {
    int L = tid & 63, n = (tid >> 6) & 3, s = (tid >> 8) & 3, v = tid >> 10;
    int q = L >> 4, ln = L & 15;
    const float* src = W + (size_t)((n * 16 + ln) * 64 + v) * 128 + s * 32 + q * 8;
    float4 a = *(const float4*)src, d = *(const float4*)(src + 4);
    *(f16x8*)(Wh + (size_t)tid * 8) = cvt8(a, d);
  } else if (tid < 66048) {
    int t2 = tid - 65536;
    int L = t2 & 63, n = (t2 >> 6) & 3, s2 = t2 >> 8;
    int q = L >> 4, ln = L & 15;
    const float* src = b + (n * 16 + ln) * 64 + s2 * 32 + q * 8;
    float4 a = *(const float4*)src, d = *(const float4*)(src + 4);
    *(f16x8*)(Bh + (size_t)t2 * 8) = cvt8(a, d);
  }
}

// async global->LDS, 16B per lane, wave-uniform LDS base (+lane*16 implicit)
typedef __attribute__((address_space(1))) const void GV;
typedef __attribute__((address_space(3))) void LV;
__device__ __forceinline__ void gload_lds16(const void* g, void* l) {
  __builtin_amdgcn_global_load_lds((GV*)g, (LV*)l, 16, 0, 0);
}

// ---- main kernel: 256 threads = 4 waves; 2-step-window LDS W stream ----
__global__ __launch_bounds__(256, 2) void edge_msg_lds(
    const float* __restrict__ Vtx, const float* __restrict__ Xe,
    const f16* __restrict__ Wh, const f16* __restrict__ Bh,
    float* __restrict__ out, int E)
{
  __shared__ f16 Wring[4 * 8192];   // 64 KB: 4 step-slots; slot of step s = s&3

  const int tid = threadIdx.x;
  const int wid = tid >> 6, lane = tid & 63;
  const int q = lane >> 4, ln = lane & 15;
  const int eoff = blockIdx.x * 256 + wid * 64;

  // ---- X fragments f16 (A[m=ln][k=q*8+j] per t,s), rows clamped ----
  int er[4];
  f16x8 xh[4][4];
  #pragma unroll
  for (int t = 0; t < 4; ++t) {
    int e = eoff + 16 * t + ln;
    er[t] = e < E ? e : E - 1;
    const float* xr = Xe + (size_t)er[t] * EDG_D;
    #pragma unroll
    for (int s = 0; s < 4; ++s) {
      float4 a = *(const float4*)(xr + s * 32 + q * 8);
      float4 d = *(const float4*)(xr + s * 32 + q * 8 + 4);
      xh[t][s] = cvt8(a, d);
    }
  }

  // ---- V chunk 0 (v = 0..7) per t, f32 -> f16x8 (registers) ----
  f16x8 vrow[4];
  #pragma unroll
  for (int t = 0; t < 4; ++t) {
    const float* vsrc = Vtx + (size_t)er[t] * VTX_D;
    float4 a = *(const float4*)(vsrc), d = *(const float4*)(vsrc + 4);
    vrow[t] = cvt8(a, d);
  }

  f32x4 acc[4][4];
  #pragma unroll
  for (int t = 0; t < 4; ++t)
    #pragma unroll
    for (int n = 0; n < 4; ++n) acc[t][n] = (f32x4){0.f, 0.f, 0.f, 0.f};

  // ---- prologue: stage steps 0..3 into slots 0..3 (batch0={0,1}, batch1={2,3}) ----
  // Wh bytes: granule (v,g) at v*16384 + g*1024 + lane*16; wave wid owns g=wid*4..+3.
  {
    const char* gb = (const char*)Wh + (size_t)wid * 4096 + (size_t)lane * 16;
    char* lb = (char*)Wring + (size_t)wid * 4096;
    #pragma unroll
    for (int s = 0; s < 4; ++s)
      #pragma unroll
      for (int c = 0; c < 4; ++c)
        gload_lds16(gb + (size_t)s * 16384 + c * 1024, lb + (size_t)s * 16384 + c * 1024);
  }

  // sync 0: batch0 (steps 0,1) done; batch1 (steps 2,3) stays in flight
  asm volatile("s_waitcnt vmcnt(8)" ::: "memory");
  __builtin_amdgcn_s_barrier();
  asm volatile("" ::: "memory");

  #pragma unroll 1
  for (int c8 = 0; c8 < 8; ++c8) {
    float4 vna[4], vnd[4];   // next V chunk (loaded in window w4==2)

    #pragma unroll
    for (int w4 = 0; w4 < 4; ++w4) {
      const int w = c8 * 4 + w4;   // window index 0..31; consumes steps {2w, 2w+1}

      // V chunk c8+1 prefetch: issued here, drained by this window's trailing sync
      if (w4 == 2 && c8 < 7) {
        #pragma unroll
        for (int t = 0; t < 4; ++t) {
          const float* vsrc = Vtx + (size_t)er[t] * VTX_D + (c8 + 1) * 8;
          vna[t] = *(const float4*)(vsrc);
          vnd[t] = *(const float4*)(vsrc + 4);
        }
      }

      // ---- window body: 2 v-steps, 128 MFMA, no syncs inside ----
      __builtin_amdgcn_s_setprio(1);
      #pragma unroll
      for (int jj = 0; jj < 2; ++jj) {
        const int j = 2 * w4 + jj;            // static 0..7: vrow extract index
        const int slot = (2 * w4 + jj) & 3;   // static: (2w+jj)&3 == (2*w4+jj)&3

        f16x2 hv[4];
        #pragma unroll
        for (int t = 0; t < 4; ++t) { f16 h = vrow[t][j]; hv[t] = (f16x2){h, h}; }

        const f16* wb = Wring + (size_t)slot * 8192 + lane * 8;
        #pragma unroll
        for (int s = 0; s < 4; ++s) {
          f16x8 bf[4];
          #pragma unroll
          for (int n = 0; n < 4; ++n) bf[n] = *(const f16x8*)(wb + (s * 4 + n) * 512);

          f16x8 af[4];
          #pragma unroll
          for (int t = 0; t < 4; ++t) {
            union { f16x8 v8; f16x2 h2[4]; } x, r;
            x.v8 = xh[t][s];
            r.h2[0] = hv[t] * x.h2[0];
            r.h2[1] = hv[t] * x.h2[1];
            r.h2[2] = hv[t] * x.h2[2];
            r.h2[3] = hv[t] * x.h2[3];
            af[t] = r.v8;
          }
          #pragma unroll
          for (int n = 0; n < 4; ++n)
            #pragma unroll
            for (int t = 0; t < 4; ++t)
              acc[t][n] = __builtin_amdgcn_mfma_f32_16x16x32_f16(af[t], bf[n], acc[t][n], 0, 0, 0);
        }
      }
      __builtin_amdgcn_s_setprio(0);

      // ---- trailing sync w+1: awaited batch is one full window stale ----
      if (w < 31) {
        asm volatile("s_waitcnt vmcnt(0)" ::: "memory");
        __builtin_amdgcn_s_barrier();
        asm volatile("" ::: "memory");   // nothing moves across the barrier

        // stage batch(w+2) = steps {2w+4, 2w+5} into the slots just freed
        if (w <= 29) {
          const int s0 = 2 * w + 4;
          const int sl0 = (2 * w4 + 0) & 3;   // == (s0)&3, static
          const int sl1 = (2 * w4 + 1) & 3;   // == (s0+1)&3, static
          const char* gb = (const char*)Wh + (size_t)s0 * 16384 +
                           (size_t)wid * 4096 + (size_t)lane * 16;
          char* lb0 = (char*)Wring + (size_t)sl0 * 16384 + (size_t)wid * 4096;
          char* lb1 = (char*)Wring + (size_t)sl1 * 16384 + (size_t)wid * 4096;
          #pragma unroll
          for (int c = 0; c < 4; ++c) gload_lds16(gb + c * 1024, lb0 + c * 1024);
          #pragma unroll
          for (int c = 0; c < 4; ++c) gload_lds16(gb + 16384 + c * 1024, lb1 + c * 1024);
        }
      }
    }

    if (c8 < 7) {
      #pragma unroll
      for (int t = 0; t < 4; ++t) vrow[t] = cvt8(vna[t], vnd[t]);
    }
  }

  // ---- bias: 2 K-steps, A = V-frags (original layout), B = Bh frags ----
  #pragma unroll
  for (int s2 = 0; s2 < 2; ++s2) {
    f16x8 av[4];
    #pragma unroll
    for (int t = 0; t < 4; ++t) {
      const float* vr2 = Vtx + (size_t)er[t] * VTX_D + s2 * 32 + q * 8;
      float4 a = *(const float4*)vr2, d = *(const float4*)(vr2 + 4);
      av[t] = cvt8(a, d);
    }
    #pragma unroll
    for (int n = 0; n < 4; ++n) {
      f16x8 bfb = *(const f16x8*)(Bh + (size_t)((s2 * 4 + n) * 64 + lane) * 8);
      #pragma unroll
      for (int t = 0; t < 4; ++t)
        acc[t][n] = __builtin_amdgcn_mfma_f32_16x16x32_f16(av[t], bfb, acc[t][n], 0, 0, 0);
    }
  }

  // ---- store: C layout col=lane&15 (m), row=q*4+r (edge) [m89-verified] ----
  #pragma unroll
  for (int t = 0; t < 4; ++t)
    #pragma unroll
    for (int r = 0; r < 4; ++r) {
      int e = eoff + 16 * t + 4 * q + r;
      if (e < E) {
        float* orow = out + (size_t)e * MSG_D;
        #pragma unroll
        for (int n = 0; n < 4; ++n) orow[n * 16 + ln] = acc[t][n][r];
      }
    }
}

// ---- fallback (workspace too small / unexpected shape): exact fp32 ----
__global__ void edge_msg_naive(const float* __restrict__ Vtx, const float* __restrict__ Xe,
                               const float* __restrict__ W, const float* __restrict__ b,
                               float* __restrict__ out, int E) {
  __shared__ float xs[EDG_D];
  __shared__ float vs[VTX_D];
  int e = blockIdx.x;
  int m = threadIdx.x;
  for (int i = m; i < EDG_D; i += 64) xs[i] = Xe[(size_t)e * EDG_D + i];
  for (int i = m; i < VTX_D; i += 64) vs[i] = Vtx[(size_t)e * VTX_D + i];
  __syncthreads();
  float s = 0.f;
  for (int v = 0; v < VTX_D; ++v) {
    const float* wr = W + (size_t)(m * 64 + v) * EDG_D;
    float p = b[m * 64 + v];
    for (int k = 0; k < EDG_D; ++k) p += xs[k] * wr[k];
    s += p * vs[v];
  }
  out[(size_t)e * MSG_D + m] = s;
}

extern "C" void kernel_launch(void* const* d_in, const int* in_sizes, int n_in,
                              void* d_out, int out_size, void* d_ws, size_t ws_size,
                              hipStream_t stream) {
  const float* Vtx = (const float*)d_in[0];   // [E, 64]
  const float* Xe  = (const float*)d_in[1];   // [E, 128]
  const float* W   = (const float*)d_in[2];   // [4096, 128]
  const float* b   = (const float*)d_in[3];   // [4096]
  float* out = (float*)d_out;

  const int E  = in_sizes[0] / VTX_D;
  const int nW = in_sizes[2];                 // 524288
  const int nb = in_sizes[3];                 // 4096

  const size_t needW = (size_t)(524288 + 4096) * sizeof(f16);   // ~1.01 MB

  if (nW != 524288 || nb != 4096 || ws_size < needW) {
    edge_msg_naive<<<E, 64, 0, stream>>>(Vtx, Xe, W, b, out, E);
    return;
  }

  f16* Wh = (f16*)d_ws;
  f16* Bh = Wh + 524288;

  prep_w<<<258, 256, 0, stream>>>(W, b, Wh, Bh);

  int blocks = (E + 255) / 256;
  edge_msg_lds<<<blocks, 256, 0, stream>>>(Vtx, Xe, Wh, Bh, out, E);
}

// Round 7
// 202.466 us; speedup vs baseline: 3.1935x; 1.0007x over previous
//
#include <hip/hip_runtime.h>
#include <stdint.h>

// EdgeMessage: message[e,m] = sum_v (edges[e,:]@W[m*64+v,:] + b[m*64+v]) * vertices[e,v]
// R13: R12 + anti-phase offset for co-resident block pairs. Single-variable probe.
//  - Ledger: R9 (L2 hotspot) null, R11 (prefetch depth) null, R12 (sync cadence:
//    64->33 syncs) null at -3us. MfmaUtil pinned ~36%. Per-window accounting on a
//    2-block CU: matrix demand ~4960 cyc, wall ~9100 -> ~4100 cyc stall that is
//    sync-count-invariant. Hypothesis: the two blocks/CU are PHASE-LOCKED (same
//    launch, same barrier cadence) -> stalls correlated -> TLP can't cover them.
//  - Fix: dispatch is XCD-major round-robin -> CU c hosts bids {c, c+256}.
//    Round-1 blocks (bid & 256) take a one-time ~2880-cycle s_sleep at entry
//    (~half a window). Their waits then overlap round-0's MFMA bursts and vice
//    versa. B trails A in the W stream by ~1us -> rides A's hot L2 lines.
//  - Everything else identical to R12 (2-step windows, 4x16KB ring, stale vmcnt(0),
//    V in registers, bias as 2 K-steps, phase-locked groups preserved).

typedef _Float16 f16;
typedef __attribute__((ext_vector_type(2))) _Float16 f16x2;
typedef __attribute__((ext_vector_type(8))) _Float16 f16x8;
typedef __attribute__((ext_vector_type(4))) float f32x4;

#define MSG_D 64
#define VTX_D 64
#define EDG_D 128

__device__ __forceinline__ f16x8 cvt8(float4 a, float4 d) {
  return (f16x8){(f16)a.x, (f16)a.y, (f16)a.z, (f16)a.w,
                 (f16)d.x, (f16)d.y, (f16)d.z, (f16)d.w};
}

// ---- prep: W -> fragment stream; b -> bias frags (layout same as R5..R12) ----
// Wh granule tid = (v*16 + c)*64 + lane (c = s*4+n): f16[8] =
//   W[(n*16+ln)*64 + v][s*32 + q*8 + j], lane = q*16+ln.
__global__ void prep_w(const float* __restrict__ W, const float* __restrict__ b,
                       f16* __restrict__ Wh, f16* __restrict__ Bh) {
  int tid = blockIdx.x * 256 + threadIdx.x;
  if (tid < 65536) {
    int L = tid & 63, n = (tid >> 6) & 3, s = (tid >> 8) & 3, v = tid >> 10;
    int q = L >> 4, ln = L & 15;
    const float* src = W + (size_t)((n * 16 + ln) * 64 + v) * 128 + s * 32 + q * 8;
    float4 a = *(const float4*)src, d = *(const float4*)(src + 4);
    *(f16x8*)(Wh + (size_t)tid * 8) = cvt8(a, d);
  } else if (tid < 66048) {
    int t2 = tid - 65536;
    int L = t2 & 63, n = (t2 >> 6) & 3, s2 = t2 >> 8;
    int q = L >> 4, ln = L & 15;
    const float* src = b + (n * 16 + ln) * 64 + s2 * 32 + q * 8;
    float4 a = *(const float4*)src, d = *(const float4*)(src + 4);
    *(f16x8*)(Bh + (size_t)t2 * 8) = cvt8(a, d);
  }
}

// async global->LDS, 16B per lane, wave-uniform LDS base (+lane*16 implicit)
typedef __attribute__((address_space(1))) const void GV;
typedef __attribute__((address_space(3))) void LV;
__device__ __forceinline__ void gload_lds16(const void* g, void* l) {
  __builtin_amdgcn_global_load_lds((GV*)g, (LV*)l, 16, 0, 0);
}

// ---- main kernel: 256 threads = 4 waves; 2-step-window LDS W stream ----
__global__ __launch_bounds__(256, 2) void edge_msg_lds(
    const float* __restrict__ Vtx, const float* __restrict__ Xe,
    const f16* __restrict__ Wh, const f16* __restrict__ Bh,
    float* __restrict__ out, int E)
{
  __shared__ f16 Wring[4 * 8192];   // 64 KB: 4 step-slots; slot of step s = s&3

  const int tid = threadIdx.x;
  const int wid = tid >> 6, lane = tid & 63;
  const int q = lane >> 4, ln = lane & 15;
  const int eoff = blockIdx.x * 256 + wid * 64;

  // ---- anti-phase: round-1 blocks (co-resident partner of round-0 on same CU)
  // sleep ~2880 cycles = ~half a window, decorrelating the pair's stalls.
  if (blockIdx.x & 256) {
    __builtin_amdgcn_s_sleep(15);
    __builtin_amdgcn_s_sleep(15);
    __builtin_amdgcn_s_sleep(15);
  }

  // ---- X fragments f16 (A[m=ln][k=q*8+j] per t,s), rows clamped ----
  int er[4];
  f16x8 xh[4][4];
  #pragma unroll
  for (int t = 0; t < 4; ++t) {
    int e = eoff + 16 * t + ln;
    er[t] = e < E ? e : E - 1;
    const float* xr = Xe + (size_t)er[t] * EDG_D;
    #pragma unroll
    for (int s = 0; s < 4; ++s) {
      float4 a = *(const float4*)(xr + s * 32 + q * 8);
      float4 d = *(const float4*)(xr + s * 32 + q * 8 + 4);
      xh[t][s] = cvt8(a, d);
    }
  }

  // ---- V chunk 0 (v = 0..7) per t, f32 -> f16x8 (registers) ----
  f16x8 vrow[4];
  #pragma unroll
  for (int t = 0; t < 4; ++t) {
    const float* vsrc = Vtx + (size_t)er[t] * VTX_D;
    float4 a = *(const float4*)(vsrc), d = *(const float4*)(vsrc + 4);
    vrow[t] = cvt8(a, d);
  }

  f32x4 acc[4][4];
  #pragma unroll
  for (int t = 0; t < 4; ++t)
    #pragma unroll
    for (int n = 0; n < 4; ++n) acc[t][n] = (f32x4){0.f, 0.f, 0.f, 0.f};

  // ---- prologue: stage steps 0..3 into slots 0..3 (batch0={0,1}, batch1={2,3}) ----
  // Wh bytes: granule (v,g) at v*16384 + g*1024 + lane*16; wave wid owns g=wid*4..+3.
  {
    const char* gb = (const char*)Wh + (size_t)wid * 4096 + (size_t)lane * 16;
    char* lb = (char*)Wring + (size_t)wid * 4096;
    #pragma unroll
    for (int s = 0; s < 4; ++s)
      #pragma unroll
      for (int c = 0; c < 4; ++c)
        gload_lds16(gb + (size_t)s * 16384 + c * 1024, lb + (size_t)s * 16384 + c * 1024);
  }

  // sync 0: batch0 (steps 0,1) done; batch1 (steps 2,3) stays in flight
  asm volatile("s_waitcnt vmcnt(8)" ::: "memory");
  __builtin_amdgcn_s_barrier();
  asm volatile("" ::: "memory");

  #pragma unroll 1
  for (int c8 = 0; c8 < 8; ++c8) {
    float4 vna[4], vnd[4];   // next V chunk (loaded in window w4==2)

    #pragma unroll
    for (int w4 = 0; w4 < 4; ++w4) {
      const int w = c8 * 4 + w4;   // window index 0..31; consumes steps {2w, 2w+1}

      // V chunk c8+1 prefetch: issued here, drained by this window's trailing sync
      if (w4 == 2 && c8 < 7) {
        #pragma unroll
        for (int t = 0; t < 4; ++t) {
          const float* vsrc = Vtx + (size_t)er[t] * VTX_D + (c8 + 1) * 8;
          vna[t] = *(const float4*)(vsrc);
          vnd[t] = *(const float4*)(vsrc + 4);
        }
      }

      // ---- window body: 2 v-steps, 128 MFMA, no syncs inside ----
      __builtin_amdgcn_s_setprio(1);
      #pragma unroll
      for (int jj = 0; jj < 2; ++jj) {
        const int j = 2 * w4 + jj;            // static 0..7: vrow extract index
        const int slot = (2 * w4 + jj) & 3;   // static: (2w+jj)&3 == (2*w4+jj)&3

        f16x2 hv[4];
        #pragma unroll
        for (int t = 0; t < 4; ++t) { f16 h = vrow[t][j]; hv[t] = (f16x2){h, h}; }

        const f16* wb = Wring + (size_t)slot * 8192 + lane * 8;
        #pragma unroll
        for (int s = 0; s < 4; ++s) {
          f16x8 bf[4];
          #pragma unroll
          for (int n = 0; n < 4; ++n) bf[n] = *(const f16x8*)(wb + (s * 4 + n) * 512);

          f16x8 af[4];
          #pragma unroll
          for (int t = 0; t < 4; ++t) {
            union { f16x8 v8; f16x2 h2[4]; } x, r;
            x.v8 = xh[t][s];
            r.h2[0] = hv[t] * x.h2[0];
            r.h2[1] = hv[t] * x.h2[1];
            r.h2[2] = hv[t] * x.h2[2];
            r.h2[3] = hv[t] * x.h2[3];
            af[t] = r.v8;
          }
          #pragma unroll
          for (int n = 0; n < 4; ++n)
            #pragma unroll
            for (int t = 0; t < 4; ++t)
              acc[t][n] = __builtin_amdgcn_mfma_f32_16x16x32_f16(af[t], bf[n], acc[t][n], 0, 0, 0);
        }
      }
      __builtin_amdgcn_s_setprio(0);

      // ---- trailing sync w+1: awaited batch is one full window stale ----
      if (w < 31) {
        asm volatile("s_waitcnt vmcnt(0)" ::: "memory");
        __builtin_amdgcn_s_barrier();
        asm volatile("" ::: "memory");   // nothing moves across the barrier

        // stage batch(w+2) = steps {2w+4, 2w+5} into the slots just freed
        if (w <= 29) {
          const int s0 = 2 * w + 4;
          const int sl0 = (2 * w4 + 0) & 3;   // == (s0)&3, static
          const int sl1 = (2 * w4 + 1) & 3;   // == (s0+1)&3, static
          const char* gb = (const char*)Wh + (size_t)s0 * 16384 +
                           (size_t)wid * 4096 + (size_t)lane * 16;
          char* lb0 = (char*)Wring + (size_t)sl0 * 16384 + (size_t)wid * 4096;
          char* lb1 = (char*)Wring + (size_t)sl1 * 16384 + (size_t)wid * 4096;
          #pragma unroll
          for (int c = 0; c < 4; ++c) gload_lds16(gb + c * 1024, lb0 + c * 1024);
          #pragma unroll
          for (int c = 0; c < 4; ++c) gload_lds16(gb + 16384 + c * 1024, lb1 + c * 1024);
        }
      }
    }

    if (c8 < 7) {
      #pragma unroll
      for (int t = 0; t < 4; ++t) vrow[t] = cvt8(vna[t], vnd[t]);
    }
  }

  // ---- bias: 2 K-steps, A = V-frags (original layout), B = Bh frags ----
  #pragma unroll
  for (int s2 = 0; s2 < 2; ++s2) {
    f16x8 av[4];
    #pragma unroll
    for (int t = 0; t < 4; ++t) {
      const float* vr2 = Vtx + (size_t)er[t] * VTX_D + s2 * 32 + q * 8;
      float4 a = *(const float4*)vr2, d = *(const float4*)(vr2 + 4);
      av[t] = cvt8(a, d);
    }
    #pragma unroll
    for (int n = 0; n < 4; ++n) {
      f16x8 bfb = *(const f16x8*)(Bh + (size_t)((s2 * 4 + n) * 64 + lane) * 8);
      #pragma unroll
      for (int t = 0; t < 4; ++t)
        acc[t][n] = __builtin_amdgcn_mfma_f32_16x16x32_f16(av[t], bfb, acc[t][n], 0, 0, 0);
    }
  }

  // ---- store: C layout col=lane&15 (m), row=q*4+r (edge) [m89-verified] ----
  #pragma unroll
  for (int t = 0; t < 4; ++t)
    #pragma unroll
    for (int r = 0; r < 4; ++r) {
      int e = eoff + 16 * t + 4 * q + r;
      if (e < E) {
        float* orow = out + (size_t)e * MSG_D;
        #pragma unroll
        for (int n = 0; n < 4; ++n) orow[n * 16 + ln] = acc[t][n][r];
      }
    }
}

// ---- fallback (workspace too small / unexpected shape): exact fp32 ----
__global__ void edge_msg_naive(const float* __restrict__ Vtx, const float* __restrict__ Xe,
                               const float* __restrict__ W, const float* __restrict__ b,
                               float* __restrict__ out, int E) {
  __shared__ float xs[EDG_D];
  __shared__ float vs[VTX_D];
  int e = blockIdx.x;
  int m = threadIdx.x;
  for (int i = m; i < EDG_D; i += 64) xs[i] = Xe[(size_t)e * EDG_D + i];
  for (int i = m; i < VTX_D; i += 64) vs[i] = Vtx[(size_t)e * VTX_D + i];
  __syncthreads();
  float s = 0.f;
  for (int v = 0; v < VTX_D; ++v) {
    const float* wr = W + (size_t)(m * 64 + v) * EDG_D;
    float p = b[m * 64 + v];
    for (int k = 0; k < EDG_D; ++k) p += xs[k] * wr[k];
    s += p * vs[v];
  }
  out[(size_t)e * MSG_D + m] = s;
}

extern "C" void kernel_launch(void* const* d_in, const int* in_sizes, int n_in,
                              void* d_out, int out_size, void* d_ws, size_t ws_size,
                              hipStream_t stream) {
  const float* Vtx = (const float*)d_in[0];   // [E, 64]
  const float* Xe  = (const float*)d_in[1];   // [E, 128]
  const float* W   = (const float*)d_in[2];   // [4096, 128]
  const float* b   = (const float*)d_in[3];   // [4096]
  float* out = (float*)d_out;

  const int E  = in_sizes[0] / VTX_D;
  const int nW = in_sizes[2];                 // 524288
  const int nb = in_sizes[3];                 // 4096

  const size_t needW = (size_t)(524288 + 4096) * sizeof(f16);   // ~1.01 MB

  if (nW != 524288 || nb != 4096 || ws_size < needW) {
    edge_msg_naive<<<E, 64, 0, stream>>>(Vtx, Xe, W, b, out, E);
    return;
  }

  f16* Wh = (f16*)d_ws;
  f16* Bh = Wh + 524288;

  prep_w<<<258, 256, 0, stream>>>(W, b, Wh, Bh);

  int blocks = (E + 255) / 256;
  edge_msg_lds<<<blocks, 256, 0, stream>>>(Vtx, Xe, Wh, Bh, out, E);
}